// Round 1
// baseline (24.206 us; speedup 1.0000x reference)
//
#include <hip/hip_runtime.h>

// YOLO loss forward, MI355X. Memory-bound streaming reduction.
// pred/target: (2048, 14, 14, 30) fp32, channel-innermost contiguous.

constexpr int N_IMG = 2048;
constexpr int NC    = 30;
constexpr int CELLS = N_IMG * 14 * 14;   // 401408
constexpr int BLOCK = 256;
constexpr int CPB   = 256;               // cells per block
constexpr int GRID  = CELLS / CPB;       // 1568 (exact)

__global__ __launch_bounds__(BLOCK)
void yolo_partial(const float* __restrict__ pred,
                  const float* __restrict__ targ,
                  float* __restrict__ partial)
{
    __shared__ float sp[CPB * NC];       // 30720 B
    __shared__ float st[CPB * NC];       // 30720 B
    __shared__ float wsum[BLOCK / 64];

    const int tid = threadIdx.x;
    const size_t base = (size_t)blockIdx.x * (size_t)(CPB * NC);

    // ---- stage global -> LDS, float4-coalesced (base is 16B-aligned: 30720*bid) ----
    const float4* gp = reinterpret_cast<const float4*>(pred + base);
    const float4* gt = reinterpret_cast<const float4*>(targ + base);
    float4* lp = reinterpret_cast<float4*>(sp);
    float4* lt = reinterpret_cast<float4*>(st);
    constexpr int NV = CPB * NC / 4;     // 1920 float4s per array
    #pragma unroll
    for (int i = 0; i < NV / BLOCK; ++i) {      // 7 full rounds
        lp[tid + i * BLOCK] = gp[tid + i * BLOCK];
        lt[tid + i * BLOCK] = gt[tid + i * BLOCK];
    }
    if (tid < NV - (NV / BLOCK) * BLOCK) {      // remainder 128
        const int i = (NV / BLOCK) * BLOCK + tid;
        lp[i] = gp[i];
        lt[i] = gt[i];
    }
    __syncthreads();

    // ---- per-thread: one cell ----
    float pv[NC], tv[NC];
    {
        // t*30 floats = t*120 B: 8B-aligned -> float2 LDS reads ok
        const float2* p2 = reinterpret_cast<const float2*>(sp + tid * NC);
        const float2* t2 = reinterpret_cast<const float2*>(st + tid * NC);
        #pragma unroll
        for (int i = 0; i < NC / 2; ++i) {
            float2 a = p2[i]; pv[2*i] = a.x; pv[2*i+1] = a.y;
            float2 b = t2[i]; tv[2*i] = b.x; tv[2*i+1] = b.y;
        }
    }

    const float coo = (tv[4] > 0.0f) ? 1.0f : 0.0f;

    // target box 0 -> xyxy (mirror reference op order)
    const float txc = tv[0] / 14.0f, tyc = tv[1] / 14.0f;
    const float tx1 = txc - 0.5f * tv[2], ty1 = tyc - 0.5f * tv[3];
    const float tx2 = txc + 0.5f * tv[2], ty2 = tyc + 0.5f * tv[3];
    const float t_area = (tx2 - tx1) * (ty2 - ty1);

    float iou0, iou1;
    {
        const float xc = pv[0] / 14.0f, yc = pv[1] / 14.0f;
        const float x1 = xc - 0.5f * pv[2], y1 = yc - 0.5f * pv[3];
        const float x2 = xc + 0.5f * pv[2], y2 = yc + 0.5f * pv[3];
        const float a1 = (x2 - x1) * (y2 - y1);
        const float wx = fmaxf(fminf(x2, tx2) - fmaxf(x1, tx1), 0.0f);
        const float wy = fmaxf(fminf(y2, ty2) - fmaxf(y1, ty1), 0.0f);
        const float inter = wx * wy;
        iou0 = inter / (a1 + t_area - inter);
    }
    {
        const float xc = pv[5] / 14.0f, yc = pv[6] / 14.0f;
        const float x1 = xc - 0.5f * pv[7], y1 = yc - 0.5f * pv[8];
        const float x2 = xc + 0.5f * pv[7], y2 = yc + 0.5f * pv[8];
        const float a1 = (x2 - x1) * (y2 - y1);
        const float wx = fmaxf(fminf(x2, tx2) - fmaxf(x1, tx1), 0.0f);
        const float wy = fmaxf(fminf(y2, ty2) - fmaxf(y1, ty1), 0.0f);
        const float inter = wx * wy;
        iou1 = inter / (a1 + t_area - inter);
    }

    // jnp.argmax: first max -> r=1 only if iou1 strictly greater.
    // Static-index selects (v_cndmask), NOT runtime array indexing (rule #20).
    const bool sel = iou1 > iou0;
    const float rp0 = sel ? pv[5] : pv[0];
    const float rp1 = sel ? pv[6] : pv[1];
    const float rp2 = sel ? pv[7] : pv[2];
    const float rp3 = sel ? pv[8] : pv[3];
    const float rp4 = sel ? pv[9] : pv[4];
    const float rt0 = sel ? tv[5] : tv[0];
    const float rt1 = sel ? tv[6] : tv[1];
    const float rt2 = sel ? tv[7] : tv[2];
    const float rt3 = sel ? tv[8] : tv[3];
    const float nrp4 = sel ? pv[4] : pv[9];

    const float d0 = rp0 - rt0, d1 = rp1 - rt1;
    const float d2 = sqrtf(rp2) - sqrtf(rt2);
    const float d3 = sqrtf(rp3) - sqrtf(rt3);
    const float loc     = d0*d0 + d1*d1 + d2*d2 + d3*d3;
    const float contain = rp4 * rp4;
    const float notc    = nrp4 * nrp4;
    const float e4 = pv[4] - tv[4], e9 = pv[9] - tv[9];
    const float noobj = e4*e4 + e9*e9;
    float cls = 0.0f;
    #pragma unroll
    for (int c = 10; c < NC; ++c) { const float d = pv[c] - tv[c]; cls += d*d; }

    float cell = coo * (5.0f * loc + 2.0f * contain + notc + cls)
               + (1.0f - coo) * (0.5f * noobj);

    // ---- block reduction (wave64 shuffle + LDS) ----
    #pragma unroll
    for (int o = 32; o > 0; o >>= 1) cell += __shfl_down(cell, o, 64);
    if ((tid & 63) == 0) wsum[tid >> 6] = cell;
    __syncthreads();
    if (tid == 0)
        partial[blockIdx.x] = wsum[0] + wsum[1] + wsum[2] + wsum[3];
}

__global__ __launch_bounds__(256)
void yolo_final(const float* __restrict__ partial, float* __restrict__ out)
{
    const int tid = threadIdx.x;
    double s = 0.0;
    for (int i = tid; i < GRID; i += 256) s += (double)partial[i];
    #pragma unroll
    for (int o = 32; o > 0; o >>= 1) s += __shfl_down(s, o, 64);
    __shared__ double w[4];
    if ((tid & 63) == 0) w[tid >> 6] = s;
    __syncthreads();
    if (tid == 0) out[0] = (float)((w[0] + w[1] + w[2] + w[3]) / (double)N_IMG);
}

extern "C" void kernel_launch(void* const* d_in, const int* in_sizes, int n_in,
                              void* d_out, int out_size, void* d_ws, size_t ws_size,
                              hipStream_t stream)
{
    const float* pred = (const float*)d_in[0];
    const float* targ = (const float*)d_in[1];
    float* out        = (float*)d_out;
    float* partial    = (float*)d_ws;   // GRID floats = 6272 B

    yolo_partial<<<GRID, BLOCK, 0, stream>>>(pred, targ, partial);
    yolo_final<<<1, 256, 0, stream>>>(partial, out);
}